// Round 10
// baseline (1648.369 us; speedup 1.0000x reference)
//
#include <hip/hip_runtime.h>

#define N_NODES 100000
#define EDGES   1600000
#define H 64
#define OFFPAD 100352
#define SCAN_CH 512
#define SCAN_BLKS 196   // 196*512 = 100352 >= N_NODES
#define ST 68           // fp32 LDS row stride (sage)
#define NBKT 1563       // 64-node buckets: ceil(100000/64)
#define CHUNK 16384
#define FILL_BLKS 98    // ceil(EDGES/CHUNK)

typedef unsigned int u32;
typedef short bf16x8 __attribute__((ext_vector_type(8)));
typedef float f32x4  __attribute__((ext_vector_type(4)));

// RNE fp32 -> bf16 split: x ~= hi + lo (both bf16)
__device__ __forceinline__ void bfsplit(float x, u32& h, u32& lo) {
    union { float f; u32 u; } c; c.f = x;
    u32 hu = (c.u + 0x7fffu + ((c.u >> 16) & 1u)) & 0xffff0000u;
    h = hu >> 16;
    union { u32 u; float f; } hb; hb.u = hu;
    union { float f; u32 u; } r; r.f = x - hb.f;
    lo = (r.u + 0x7fffu + ((r.u >> 16) & 1u)) >> 16;
}

// ---------- input projection via MFMA: out = relu(x @ W^T + b) ----------
template<int D>
__global__ __launch_bounds__(256) void proj_mfma(
    const float* __restrict__ x, const float* __restrict__ w,
    const float* __restrict__ b, float* __restrict__ out)
{
    constexpr int KPAD = (D + 63) & ~63;
    constexpr int NT = KPAD / 64;
    __shared__ u32 Xh[64 * 32], Xl[64 * 32], Wh[64 * 32], Wl[64 * 32];
    const int tid  = threadIdx.x;
    const int base = blockIdx.x * 64;
    const int l  = tid & 63;
    const int wv = tid >> 6;
    const int arow = wv * 16 + (l & 15);
    const int kg = l >> 4;
    f32x4 acc[4] = {};

    for (int t = 0; t < NT; ++t) {
        const int k0 = t * 64;
        for (int i = tid; i < 2048; i += 256) {
            const int row = i >> 5, u = i & 31;
            const int k = k0 + 2 * u;
            const int widx = (row << 5) | (u ^ ((row & 7) << 2));
            {
                const int rr = min(base + row, N_NODES - 1);
                float2 v = make_float2(0.f, 0.f);
                if (k + 2 <= D) v = *(const float2*)&x[(size_t)rr * D + k];
                u32 h0, l0, h1, l1;
                bfsplit(v.x, h0, l0); bfsplit(v.y, h1, l1);
                Xh[widx] = h0 | (h1 << 16);
                Xl[widx] = l0 | (l1 << 16);
            }
            {
                float2 v = make_float2(0.f, 0.f);
                if (k + 2 <= D) v = *(const float2*)&w[(size_t)row * D + k];
                u32 h0, l0, h1, l1;
                bfsplit(v.x, h0, l0); bfsplit(v.y, h1, l1);
                Wh[widx] = h0 | (h1 << 16);
                Wl[widx] = l0 | (l1 << 16);
            }
        }
        __syncthreads();
        #pragma unroll
        for (int s = 0; s < 2; ++s) {
            const int ka = (arow << 5) + ((s * 16 + kg * 4) ^ ((arow & 7) << 2));
            const bf16x8 ah = *(const bf16x8*)&Xh[ka];
            const bf16x8 al = *(const bf16x8*)&Xl[ka];
            #pragma unroll
            for (int c = 0; c < 4; ++c) {
                const int brow = c * 16 + (l & 15);
                const int kb = (brow << 5) + ((s * 16 + kg * 4) ^ ((brow & 7) << 2));
                const bf16x8 bh = *(const bf16x8*)&Wh[kb];
                const bf16x8 bl = *(const bf16x8*)&Wl[kb];
                acc[c] = __builtin_amdgcn_mfma_f32_16x16x32_bf16(ah, bh, acc[c], 0, 0, 0);
                acc[c] = __builtin_amdgcn_mfma_f32_16x16x32_bf16(ah, bl, acc[c], 0, 0, 0);
                acc[c] = __builtin_amdgcn_mfma_f32_16x16x32_bf16(al, bh, acc[c], 0, 0, 0);
            }
        }
        __syncthreads();
    }

    const int orow0 = base + wv * 16 + (l >> 4) * 4;
    #pragma unroll
    for (int c = 0; c < 4; ++c) {
        const int col = c * 16 + (l & 15);
        const float bv = b[col];
        #pragma unroll
        for (int i = 0; i < 4; ++i) {
            const int row = orow0 + i;
            if (row < N_NODES)
                out[(size_t)row * H + col] = fmaxf(acc[c][i] + bv, 0.f);
        }
    }
}

// ---------- histogram of dst (per node) ----------
__global__ __launch_bounds__(256) void hist_dst(
    const int* __restrict__ ei, int* __restrict__ hist)
{
    int e = blockIdx.x * 256 + threadIdx.x;
    if (e < EDGES) atomicAdd(&hist[ei[EDGES + e]], 1);
}

// ---------- device-wide scan over per-node hist -> bucket offsets ----------
__global__ __launch_bounds__(256) void scan_partial(
    const int* __restrict__ hist, int* __restrict__ bsum)
{
    __shared__ int red[256];
    const int b = blockIdx.x, t = threadIdx.x;
    const int i0 = b * SCAN_CH + t;
    int s = 0;
    if (i0 < N_NODES) s += hist[i0];
    if (i0 + 256 < N_NODES) s += hist[i0 + 256];
    red[t] = s;
    __syncthreads();
    for (int d = 128; d > 0; d >>= 1) {
        if (t < d) red[t] += red[t + d];
        __syncthreads();
    }
    if (t == 0) bsum[b] = red[0];
}

__global__ __launch_bounds__(256) void scan_tops(
    const int* __restrict__ bsum, int* __restrict__ bpre)
{
    __shared__ int s[256];
    const int t = threadIdx.x;
    const int v = (t < SCAN_BLKS) ? bsum[t] : 0;
    s[t] = v;
    __syncthreads();
    for (int d = 1; d < 256; d <<= 1) {
        int x = (t >= d) ? s[t - d] : 0;
        __syncthreads();
        s[t] += x;
        __syncthreads();
    }
    if (t < SCAN_BLKS) bpre[t] = s[t] - v;
}

// writes bucket offsets (boff) and sort cursors (gcur) at 64-node granularity
__global__ __launch_bounds__(512) void scan_apply(
    const int* __restrict__ hist, const int* __restrict__ bpre,
    int* __restrict__ boff, int* __restrict__ gcur)
{
    __shared__ int s[512];
    const int b = blockIdx.x, t = threadIdx.x;
    const int i = b * SCAN_CH + t;
    const int h = (i < N_NODES) ? hist[i] : 0;
    s[t] = h;
    __syncthreads();
    for (int d = 1; d < 512; d <<= 1) {
        int x = (t >= d) ? s[t - d] : 0;
        __syncthreads();
        s[t] += x;
        __syncthreads();
    }
    if (i < N_NODES && (i & 63) == 0) {
        const int excl = s[t] - h + bpre[b];
        boff[i >> 6] = excl;
        gcur[i >> 6] = excl;
    }
    if (b == 0 && t == 0) boff[NBKT] = EDGES;
}

// ---------- chunked counting-sort fill: each block owns contiguous runs ----------
// csr entry = (src<<6) | (dst&63); bucket = dst>>6. Handles both edge types.
__global__ __launch_bounds__(256) void sort_fill(
    const int* __restrict__ ei_p, const int* __restrict__ ei_b,
    int* __restrict__ gcur_p, int* __restrict__ gcur_b,
    int* __restrict__ csr_p, int* __restrict__ csr_b)
{
    __shared__ u32 cnt[NBKT];
    __shared__ u32 base[NBKT];
    int b = blockIdx.x;
    const int* __restrict__ ei; int* __restrict__ gcur; int* __restrict__ csr;
    if (b < FILL_BLKS) { ei = ei_p; gcur = gcur_p; csr = csr_p; }
    else { b -= FILL_BLKS; ei = ei_b; gcur = gcur_b; csr = csr_b; }
    const int tid = threadIdx.x;
    const int e0 = b * CHUNK, e1 = min(e0 + CHUNK, EDGES);

    for (int i = tid; i < NBKT; i += 256) cnt[i] = 0;
    __syncthreads();
    for (int e = e0 + tid; e < e1; e += 256)
        atomicAdd(&cnt[ei[EDGES + e] >> 6], 1u);
    __syncthreads();
    for (int i = tid; i < NBKT; i += 256) {
        const u32 c = cnt[i];
        base[i] = c ? (u32)atomicAdd(&gcur[i], (int)c) : 0u;
        cnt[i] = 0;
    }
    __syncthreads();
    for (int e = e0 + tid; e < e1; e += 256) {
        const int d = ei[EDGES + e], s = ei[e];
        const int k = d >> 6;
        const u32 pos = base[k] + atomicAdd(&cnt[k], 1u);
        csr[pos] = (s << 6) | (d & 63);
    }
}

// ---------- bucket aggregation: block per 64-node bucket, LDS fp32 accumulators ----------
__global__ __launch_bounds__(256) void bucket64_agg(
    const float* __restrict__ feat, const int* __restrict__ boff,
    const int* __restrict__ hist, const int* __restrict__ csr,
    float* __restrict__ agg)
{
    __shared__ float acc[64 * 64];   // acc[node&63][lane] -> bank = lane%32, conflict-free
    __shared__ int ids[256];
    const int k = blockIdx.x, tid = threadIdx.x;
    const int lane = tid & 63, wv = tid >> 6;

    for (int i = tid; i < 4096; i += 256) acc[i] = 0.f;
    __syncthreads();
    const int beg = boff[k], end = boff[k + 1];
    for (int t0 = beg; t0 < end; t0 += 256) {
        const int n = min(256, end - t0);
        if (tid < n) ids[tid] = csr[t0 + tid];
        __syncthreads();
        for (int i = wv; i < n; i += 4) {
            const int id = ids[i];
            const float v = feat[(size_t)(id >> 6) * H + lane];
            atomicAdd(&acc[(id & 63) * 64 + lane], v);
        }
        __syncthreads();
    }
    for (int r = wv; r < 64; r += 4) {
        const int node = (k << 6) + r;
        if (node < N_NODES) {
            const float inv = 1.0f / (float)max(hist[node], 1);
            agg[(size_t)node * H + lane] = acc[r * 64 + lane] * inv;
        }
    }
}

// ---------- fold conv2+head ----------
__global__ __launch_bounds__(256) void fold_head(
    const float* __restrict__ w_out, const float* __restrict__ wl2,
    const float* __restrict__ wr2, const float* __restrict__ bl2,
    const float* __restrict__ b_out, float* __restrict__ headW)
{
    const int t = threadIdx.x;
    if (t < 128) {
        int o = t >> 6, j = t & 63;
        float s = 0.f;
        for (int h = 0; h < 64; ++h) s += w_out[o * 64 + h] * wl2[h * 64 + j];
        headW[o * 64 + j] = s;
    } else {
        int idx = t - 128, o = idx >> 6, j = idx & 63;
        float s = 0.f;
        for (int h = 0; h < 64; ++h) s += w_out[o * 64 + h] * wr2[h * 64 + j];
        headW[128 + o * 64 + j] = s;
    }
    if (t < 2) {
        float s = b_out[t];
        for (int h = 0; h < 64; ++h) s += w_out[t * 64 + h] * bl2[h];
        headW[256 + t] = s;
    }
}

// ---------- SAGE node update: 64 rows/block, 4x4 reg tiles, 2 K-passes (fp32) ----------
template<bool ZHEAD>
__global__ __launch_bounds__(256) void sage_node(
    const float* __restrict__ agg, const float* __restrict__ xdst,
    const float* __restrict__ wl, const float* __restrict__ bl,
    const float* __restrict__ wr,
    float* __restrict__ out,
    const float* __restrict__ headW, float* __restrict__ z)
{
    __shared__ __align__(16) float At[64 * ST];
    __shared__ __align__(16) float Bt[64 * ST];
    const int tid  = threadIdx.x;
    const int base = blockIdx.x * 64;
    const int col4 = (tid & 15) * 4;
    const int row4 = (tid >> 4) * 4;
    float c[4][4];
    {
        const float4 bv = *(const float4*)&bl[col4];
        #pragma unroll
        for (int i = 0; i < 4; ++i) { c[i][0] = bv.x; c[i][1] = bv.y; c[i][2] = bv.z; c[i][3] = bv.w; }
    }

    #pragma unroll
    for (int pass = 0; pass < 2; ++pass) {
        const float* __restrict__ A = pass ? xdst : agg;
        const float* __restrict__ B = pass ? wr : wl;
        for (int idx = tid; idx < 64 * 64; idx += 256) {
            const int row = idx >> 6, k = idx & 63;
            const int rr = min(base + row, N_NODES - 1);
            At[k * ST + row] = A[(size_t)rr * H + k];
        }
        for (int idx = tid; idx < 64 * 64; idx += 256) {
            const int col = idx >> 6, k = idx & 63;
            Bt[k * ST + col] = B[col * 64 + k];
        }
        __syncthreads();
        #pragma unroll 4
        for (int k = 0; k < 64; ++k) {
            const float4 av = *(const float4*)&At[k * ST + row4];
            const float4 bv = *(const float4*)&Bt[k * ST + col4];
            c[0][0] += av.x * bv.x; c[0][1] += av.x * bv.y; c[0][2] += av.x * bv.z; c[0][3] += av.x * bv.w;
            c[1][0] += av.y * bv.x; c[1][1] += av.y * bv.y; c[1][2] += av.y * bv.z; c[1][3] += av.y * bv.w;
            c[2][0] += av.z * bv.x; c[2][1] += av.z * bv.y; c[2][2] += av.z * bv.z; c[2][3] += av.z * bv.w;
            c[3][0] += av.w * bv.x; c[3][1] += av.w * bv.y; c[3][2] += av.w * bv.z; c[3][3] += av.w * bv.w;
        }
        __syncthreads();
    }

    if (!ZHEAD) {
        #pragma unroll
        for (int i = 0; i < 4; ++i) {
            const int row = base + row4 + i;
            if (row < N_NODES) {
                float4 o;
                o.x = fmaxf(c[i][0], 0.f); o.y = fmaxf(c[i][1], 0.f);
                o.z = fmaxf(c[i][2], 0.f); o.w = fmaxf(c[i][3], 0.f);
                *(float4*)&out[(size_t)row * H + col4] = o;
            }
        }
    } else {
        float* Us = At;
        #pragma unroll
        for (int i = 0; i < 4; ++i)
            #pragma unroll
            for (int jj = 0; jj < 4; ++jj)
                Us[(row4 + i) * 65 + col4 + jj] = fmaxf(c[i][jj], 0.f);
        __syncthreads();
        if (tid < 128) {
            const int r = tid & 63, o = tid >> 6;
            const int row = base + r;
            if (row < N_NODES) {
                float v = 0.f;
                for (int k = 0; k < 64; ++k)
                    v += Us[r * 65 + k] * headW[o * 64 + k];
                z[(size_t)row * 2 + o] = v;
            }
        }
    }
}

// ---------- final: block per bucket; LDS z-acc, then wave-per-node head ----------
__global__ __launch_bounds__(256) void final2(
    const int* __restrict__ boff, const int* __restrict__ hist,
    const int* __restrict__ csr,
    const float* __restrict__ z, const float* __restrict__ a1,
    const float* __restrict__ headW, float* __restrict__ out)
{
    __shared__ float zx[64], zy[64];
    const int k = blockIdx.x, tid = threadIdx.x;
    const int lane = tid & 63, wv = tid >> 6;
    if (tid < 64) { zx[tid] = 0.f; zy[tid] = 0.f; }
    __syncthreads();
    const int beg = boff[k], end = boff[k + 1];
    for (int t0 = beg + tid; t0 < end; t0 += 256) {
        const int id = csr[t0];
        const float2 zv = *(const float2*)&z[(size_t)(id >> 6) * 2];
        atomicAdd(&zx[id & 63], zv.x);
        atomicAdd(&zy[id & 63], zv.y);
    }
    __syncthreads();
    for (int r = wv; r < 64; r += 4) {
        const int node = (k << 6) + r;
        if (node >= N_NODES) break;
        const float av = a1[(size_t)node * H + lane];
        float p0 = av * headW[128 + lane];
        float p1 = av * headW[192 + lane];
        #pragma unroll
        for (int m = 1; m <= 32; m <<= 1) {
            p0 += __shfl_xor(p0, m, 64);
            p1 += __shfl_xor(p1, m, 64);
        }
        if (lane == 0) {
            const float inv = 1.0f / (float)max(hist[node], 1);
            float2 o;
            o.x = zx[r] * inv + p0 + headW[256];
            o.y = zy[r] * inv + p1 + headW[257];
            *(float2*)&out[(size_t)node * 2] = o;
        }
    }
}

extern "C" void kernel_launch(void* const* d_in, const int* in_sizes, int n_in,
                              void* d_out, int out_size, void* d_ws, size_t ws_size,
                              hipStream_t stream) {
    const float* x_a    = (const float*)d_in[0];
    const float* x_u    = (const float*)d_in[1];
    const int*   ei_p   = (const int*)d_in[2];
    const int*   ei_b   = (const int*)d_in[3];
    const float* w_in_a = (const float*)d_in[4];
    const float* b_in_a = (const float*)d_in[5];
    const float* w_in_u = (const float*)d_in[6];
    const float* b_in_u = (const float*)d_in[7];
    const float* c1p_wl = (const float*)d_in[8];
    const float* c1p_bl = (const float*)d_in[9];
    const float* c1p_wr = (const float*)d_in[10];
    const float* c1b_wl = (const float*)d_in[11];
    const float* c1b_bl = (const float*)d_in[12];
    const float* c1b_wr = (const float*)d_in[13];
    const float* c2p_wl = (const float*)d_in[14];
    const float* c2p_bl = (const float*)d_in[15];
    const float* c2p_wr = (const float*)d_in[16];
    const float* w_out  = (const float*)d_in[20];
    const float* b_out  = (const float*)d_in[21];

    const size_t NF = (size_t)N_NODES * H;
    float* bufA  = (float*)d_ws;
    float* bufU  = bufA + NF;
    float* agg   = bufU + NF;
    float* z     = agg + NF;
    float* headW = z + 2 * N_NODES;
    int* boff_p = (int*)(headW + 512);   // NBKT+1, pad 2048
    int* boff_b = boff_p + 2048;
    int* gcur_p = boff_b + 2048;
    int* gcur_b = gcur_p + 2048;
    int* hist_p = gcur_b + 2048;
    int* hist_b = hist_p + OFFPAD;
    int* bsum_p = hist_b + OFFPAD;
    int* bsum_b = bsum_p + 256;
    int* bpre_p = bsum_b + 256;
    int* bpre_b = bpre_p + 256;
    int* csr_p  = bpre_b + 256;
    int* csr_b  = csr_p + EDGES;

    const dim3 blk(256);
    const int grid_edge = EDGES / 256;           // 6250
    const int grid_gemm = (N_NODES + 63) / 64;   // 1563

    // --- bucket offsets + counting-sort fill ---
    hipMemsetAsync(hist_p, 0, 2 * OFFPAD * sizeof(int), stream);
    hist_dst<<<grid_edge, blk, 0, stream>>>(ei_p, hist_p);
    hist_dst<<<grid_edge, blk, 0, stream>>>(ei_b, hist_b);
    scan_partial<<<SCAN_BLKS, blk, 0, stream>>>(hist_p, bsum_p);
    scan_partial<<<SCAN_BLKS, blk, 0, stream>>>(hist_b, bsum_b);
    scan_tops<<<1, blk, 0, stream>>>(bsum_p, bpre_p);
    scan_tops<<<1, blk, 0, stream>>>(bsum_b, bpre_b);
    scan_apply<<<SCAN_BLKS, 512, 0, stream>>>(hist_p, bpre_p, boff_p, gcur_p);
    scan_apply<<<SCAN_BLKS, 512, 0, stream>>>(hist_b, bpre_b, boff_b, gcur_b);
    sort_fill<<<2 * FILL_BLKS, blk, 0, stream>>>(ei_p, ei_b, gcur_p, gcur_b, csr_p, csr_b);

    // --- input projections (MFMA, bf16-split) ---
    proj_mfma<300><<<grid_gemm, blk, 0, stream>>>(x_a, w_in_a, b_in_a, bufA);
    proj_mfma<64> <<<grid_gemm, blk, 0, stream>>>(x_u, w_in_u, b_in_u, bufU);

    fold_head<<<1, blk, 0, stream>>>(w_out, c2p_wl, c2p_wr, c2p_bl, b_out, headW);

    // user side: agg articles (ei_pb), z = relu(sage)@Wl'^T (u1 never stored)
    bucket64_agg<<<NBKT, blk, 0, stream>>>(bufA, boff_b, hist_b, csr_b, agg);
    sage_node<true><<<grid_gemm, blk, 0, stream>>>(
        agg, bufU, c1b_wl, c1b_bl, c1b_wr, nullptr, headW, z);

    // article side: agg users (ei_posts), a1 in-place over bufA
    bucket64_agg<<<NBKT, blk, 0, stream>>>(bufU, boff_p, hist_p, csr_p, agg);
    sage_node<false><<<grid_gemm, blk, 0, stream>>>(
        agg, bufA, c1p_wl, c1p_bl, c1p_wr, bufA, nullptr, nullptr);

    final2<<<NBKT, blk, 0, stream>>>(boff_p, hist_p, csr_p, z, bufA, headW, (float*)d_out);

    (void)in_sizes; (void)n_in; (void)out_size; (void)ws_size;
}

// Round 11
// 558.846 us; speedup vs baseline: 2.9496x; 2.9496x over previous
//
#include <hip/hip_runtime.h>

#define N_NODES 100000
#define EDGES   1600000
#define H 64
#define OFFPAD 100352
#define SCAN_CH 512
#define SCAN_BLKS 196   // 196*512 = 100352 >= N_NODES
#define ST 68           // fp32 LDS row stride (sage)
#define NBKT 1563       // 64-node buckets
#define CHUNK 16384
#define FILL_BLKS 98    // ceil(EDGES/CHUNK)

typedef unsigned int u32;
typedef short bf16x8 __attribute__((ext_vector_type(8)));
typedef float f32x4  __attribute__((ext_vector_type(4)));

// RNE fp32 -> bf16 split: x ~= hi + lo (both bf16)
__device__ __forceinline__ void bfsplit(float x, u32& h, u32& lo) {
    union { float f; u32 u; } c; c.f = x;
    u32 hu = (c.u + 0x7fffu + ((c.u >> 16) & 1u)) & 0xffff0000u;
    h = hu >> 16;
    union { u32 u; float f; } hb; hb.u = hu;
    union { float f; u32 u; } r; r.f = x - hb.f;
    lo = (r.u + 0x7fffu + ((r.u >> 16) & 1u)) >> 16;
}

// ---------- input projection via MFMA: out = relu(x @ W^T + b) ----------
template<int D>
__global__ __launch_bounds__(256) void proj_mfma(
    const float* __restrict__ x, const float* __restrict__ w,
    const float* __restrict__ b, float* __restrict__ out)
{
    constexpr int KPAD = (D + 63) & ~63;
    constexpr int NT = KPAD / 64;
    __shared__ u32 Xh[64 * 32], Xl[64 * 32], Wh[64 * 32], Wl[64 * 32];
    const int tid  = threadIdx.x;
    const int base = blockIdx.x * 64;
    const int l  = tid & 63;
    const int wv = tid >> 6;
    const int arow = wv * 16 + (l & 15);
    const int kg = l >> 4;
    f32x4 acc[4] = {};

    for (int t = 0; t < NT; ++t) {
        const int k0 = t * 64;
        for (int i = tid; i < 2048; i += 256) {
            const int row = i >> 5, u = i & 31;
            const int k = k0 + 2 * u;
            const int widx = (row << 5) | (u ^ ((row & 7) << 2));
            {
                const int rr = min(base + row, N_NODES - 1);
                float2 v = make_float2(0.f, 0.f);
                if (k + 2 <= D) v = *(const float2*)&x[(size_t)rr * D + k];
                u32 h0, l0, h1, l1;
                bfsplit(v.x, h0, l0); bfsplit(v.y, h1, l1);
                Xh[widx] = h0 | (h1 << 16);
                Xl[widx] = l0 | (l1 << 16);
            }
            {
                float2 v = make_float2(0.f, 0.f);
                if (k + 2 <= D) v = *(const float2*)&w[(size_t)row * D + k];
                u32 h0, l0, h1, l1;
                bfsplit(v.x, h0, l0); bfsplit(v.y, h1, l1);
                Wh[widx] = h0 | (h1 << 16);
                Wl[widx] = l0 | (l1 << 16);
            }
        }
        __syncthreads();
        #pragma unroll
        for (int s = 0; s < 2; ++s) {
            const int ka = (arow << 5) + ((s * 16 + kg * 4) ^ ((arow & 7) << 2));
            const bf16x8 ah = *(const bf16x8*)&Xh[ka];
            const bf16x8 al = *(const bf16x8*)&Xl[ka];
            #pragma unroll
            for (int c = 0; c < 4; ++c) {
                const int brow = c * 16 + (l & 15);
                const int kb = (brow << 5) + ((s * 16 + kg * 4) ^ ((brow & 7) << 2));
                const bf16x8 bh = *(const bf16x8*)&Wh[kb];
                const bf16x8 bl = *(const bf16x8*)&Wl[kb];
                acc[c] = __builtin_amdgcn_mfma_f32_16x16x32_bf16(ah, bh, acc[c], 0, 0, 0);
                acc[c] = __builtin_amdgcn_mfma_f32_16x16x32_bf16(ah, bl, acc[c], 0, 0, 0);
                acc[c] = __builtin_amdgcn_mfma_f32_16x16x32_bf16(al, bh, acc[c], 0, 0, 0);
            }
        }
        __syncthreads();
    }

    const int orow0 = base + wv * 16 + (l >> 4) * 4;
    #pragma unroll
    for (int c = 0; c < 4; ++c) {
        const int col = c * 16 + (l & 15);
        const float bv = b[col];
        #pragma unroll
        for (int i = 0; i < 4; ++i) {
            const int row = orow0 + i;
            if (row < N_NODES)
                out[(size_t)row * H + col] = fmaxf(acc[c][i] + bv, 0.f);
        }
    }
}

// ---------- histogram of dst (per node) ----------
__global__ __launch_bounds__(256) void hist_dst(
    const int* __restrict__ ei, int* __restrict__ hist)
{
    int e = blockIdx.x * 256 + threadIdx.x;
    if (e < EDGES) atomicAdd(&hist[ei[EDGES + e]], 1);
}

// ---------- device-wide scan ----------
__global__ __launch_bounds__(256) void scan_partial(
    const int* __restrict__ hist, int* __restrict__ bsum)
{
    __shared__ int red[256];
    const int b = blockIdx.x, t = threadIdx.x;
    const int i0 = b * SCAN_CH + t;
    int s = 0;
    if (i0 < N_NODES) s += hist[i0];
    if (i0 + 256 < N_NODES) s += hist[i0 + 256];
    red[t] = s;
    __syncthreads();
    for (int d = 128; d > 0; d >>= 1) {
        if (t < d) red[t] += red[t + d];
        __syncthreads();
    }
    if (t == 0) bsum[b] = red[0];
}

__global__ __launch_bounds__(256) void scan_tops(
    const int* __restrict__ bsum, int* __restrict__ bpre)
{
    __shared__ int s[256];
    const int t = threadIdx.x;
    const int v = (t < SCAN_BLKS) ? bsum[t] : 0;
    s[t] = v;
    __syncthreads();
    for (int d = 1; d < 256; d <<= 1) {
        int x = (t >= d) ? s[t - d] : 0;
        __syncthreads();
        s[t] += x;
        __syncthreads();
    }
    if (t < SCAN_BLKS) bpre[t] = s[t] - v;
}

// per-node off[] + bucket offsets/cursors at 64-node granularity
__global__ __launch_bounds__(512) void scan_apply(
    const int* __restrict__ hist, const int* __restrict__ bpre,
    int* __restrict__ off, int* __restrict__ boff, int* __restrict__ gcur)
{
    __shared__ int s[512];
    const int b = blockIdx.x, t = threadIdx.x;
    const int i = b * SCAN_CH + t;
    const int h = (i < N_NODES) ? hist[i] : 0;
    s[t] = h;
    __syncthreads();
    for (int d = 1; d < 512; d <<= 1) {
        int x = (t >= d) ? s[t - d] : 0;
        __syncthreads();
        s[t] += x;
        __syncthreads();
    }
    if (i < N_NODES) {
        const int excl = s[t] - h + bpre[b];
        off[i] = excl;
        if ((i & 63) == 0) { boff[i >> 6] = excl; gcur[i >> 6] = excl; }
    }
    if (b == 0 && t == 0) { off[N_NODES] = EDGES; boff[NBKT] = EDGES; }
}

// ---------- level 1: chunked counting-sort into 64-node buckets (packed ids) ----------
__global__ __launch_bounds__(256) void sort_fill(
    const int* __restrict__ ei_p, const int* __restrict__ ei_b,
    int* __restrict__ gcur_p, int* __restrict__ gcur_b,
    int* __restrict__ raw_p, int* __restrict__ raw_b)
{
    __shared__ u32 cnt[NBKT];
    __shared__ u32 base[NBKT];
    int b = blockIdx.x;
    const int* __restrict__ ei; int* __restrict__ gcur; int* __restrict__ raw;
    if (b < FILL_BLKS) { ei = ei_p; gcur = gcur_p; raw = raw_p; }
    else { b -= FILL_BLKS; ei = ei_b; gcur = gcur_b; raw = raw_b; }
    const int tid = threadIdx.x;
    const int e0 = b * CHUNK, e1 = min(e0 + CHUNK, EDGES);

    for (int i = tid; i < NBKT; i += 256) cnt[i] = 0;
    __syncthreads();
    for (int e = e0 + tid; e < e1; e += 256)
        atomicAdd(&cnt[ei[EDGES + e] >> 6], 1u);
    __syncthreads();
    for (int i = tid; i < NBKT; i += 256) {
        const u32 c = cnt[i];
        base[i] = c ? (u32)atomicAdd(&gcur[i], (int)c) : 0u;
        cnt[i] = 0;
    }
    __syncthreads();
    for (int e = e0 + tid; e < e1; e += 256) {
        const int d = ei[EDGES + e], s = ei[e];
        const int k = d >> 6;
        const u32 pos = base[k] + atomicAdd(&cnt[k], 1u);
        raw[pos] = (s << 6) | (d & 63);
    }
}

// ---------- level 2: within-bucket scatter to exact per-node runs (block owns range) ----------
__global__ __launch_bounds__(256) void bucket_sort2(
    const int* __restrict__ raw, const int* __restrict__ off,
    const int* __restrict__ boff, int* __restrict__ csr)
{
    __shared__ int cur[64];
    const int k = blockIdx.x, tid = threadIdx.x;
    if (tid < 64) {
        const int node = (k << 6) + tid;
        cur[tid] = (node < N_NODES) ? off[node] : EDGES;
    }
    __syncthreads();
    const int beg = boff[k], end = boff[k + 1];
    for (int e = beg + tid; e < end; e += 256) {
        const int id = raw[e];
        const int pos = atomicAdd(&cur[id & 63], 1);
        csr[pos] = id >> 6;
    }
}

// ---------- gather-reduce: wave per node (register accumulation) ----------
__global__ __launch_bounds__(256) void gather_mean(
    const float* __restrict__ feat, const int* __restrict__ off,
    const int* __restrict__ csr, float* __restrict__ agg)
{
    const int node = (blockIdx.x * 256 + threadIdx.x) >> 6;
    const int lane = threadIdx.x & 63;
    const int grp  = lane >> 4;
    const int fb   = (lane & 15) * 4;
    const int beg = off[node], end = off[node + 1];
    float4 acc = make_float4(0.f, 0.f, 0.f, 0.f);
    for (int e = beg + grp; e < end; e += 4) {
        int s = csr[e];
        const float4 v = *(const float4*)&feat[(size_t)s * H + fb];
        acc.x += v.x; acc.y += v.y; acc.z += v.z; acc.w += v.w;
    }
    #pragma unroll
    for (int m = 16; m <= 32; m <<= 1) {
        acc.x += __shfl_xor(acc.x, m, 64);
        acc.y += __shfl_xor(acc.y, m, 64);
        acc.z += __shfl_xor(acc.z, m, 64);
        acc.w += __shfl_xor(acc.w, m, 64);
    }
    const float inv = 1.0f / fmaxf((float)(end - beg), 1.0f);
    acc.x *= inv; acc.y *= inv; acc.z *= inv; acc.w *= inv;
    if (grp == 0) *(float4*)&agg[(size_t)node * H + fb] = acc;
}

// ---------- fold conv2+head ----------
__global__ __launch_bounds__(256) void fold_head(
    const float* __restrict__ w_out, const float* __restrict__ wl2,
    const float* __restrict__ wr2, const float* __restrict__ bl2,
    const float* __restrict__ b_out, float* __restrict__ headW)
{
    const int t = threadIdx.x;
    if (t < 128) {
        int o = t >> 6, j = t & 63;
        float s = 0.f;
        for (int h = 0; h < 64; ++h) s += w_out[o * 64 + h] * wl2[h * 64 + j];
        headW[o * 64 + j] = s;
    } else {
        int idx = t - 128, o = idx >> 6, j = idx & 63;
        float s = 0.f;
        for (int h = 0; h < 64; ++h) s += w_out[o * 64 + h] * wr2[h * 64 + j];
        headW[128 + o * 64 + j] = s;
    }
    if (t < 2) {
        float s = b_out[t];
        for (int h = 0; h < 64; ++h) s += w_out[t * 64 + h] * bl2[h];
        headW[256 + t] = s;
    }
}

// ---------- SAGE node update: 64 rows/block, 4x4 reg tiles, 2 K-passes (fp32) ----------
template<bool ZHEAD>
__global__ __launch_bounds__(256) void sage_node(
    const float* __restrict__ agg, const float* __restrict__ xdst,
    const float* __restrict__ wl, const float* __restrict__ bl,
    const float* __restrict__ wr,
    float* __restrict__ out,
    const float* __restrict__ headW, float* __restrict__ z)
{
    __shared__ __align__(16) float At[64 * ST];
    __shared__ __align__(16) float Bt[64 * ST];
    const int tid  = threadIdx.x;
    const int base = blockIdx.x * 64;
    const int col4 = (tid & 15) * 4;
    const int row4 = (tid >> 4) * 4;
    float c[4][4];
    {
        const float4 bv = *(const float4*)&bl[col4];
        #pragma unroll
        for (int i = 0; i < 4; ++i) { c[i][0] = bv.x; c[i][1] = bv.y; c[i][2] = bv.z; c[i][3] = bv.w; }
    }

    #pragma unroll
    for (int pass = 0; pass < 2; ++pass) {
        const float* __restrict__ A = pass ? xdst : agg;
        const float* __restrict__ B = pass ? wr : wl;
        for (int idx = tid; idx < 64 * 64; idx += 256) {
            const int row = idx >> 6, k = idx & 63;
            const int rr = min(base + row, N_NODES - 1);
            At[k * ST + row] = A[(size_t)rr * H + k];
        }
        for (int idx = tid; idx < 64 * 64; idx += 256) {
            const int col = idx >> 6, k = idx & 63;
            Bt[k * ST + col] = B[col * 64 + k];
        }
        __syncthreads();
        #pragma unroll 4
        for (int k = 0; k < 64; ++k) {
            const float4 av = *(const float4*)&At[k * ST + row4];
            const float4 bv = *(const float4*)&Bt[k * ST + col4];
            c[0][0] += av.x * bv.x; c[0][1] += av.x * bv.y; c[0][2] += av.x * bv.z; c[0][3] += av.x * bv.w;
            c[1][0] += av.y * bv.x; c[1][1] += av.y * bv.y; c[1][2] += av.y * bv.z; c[1][3] += av.y * bv.w;
            c[2][0] += av.z * bv.x; c[2][1] += av.z * bv.y; c[2][2] += av.z * bv.z; c[2][3] += av.z * bv.w;
            c[3][0] += av.w * bv.x; c[3][1] += av.w * bv.y; c[3][2] += av.w * bv.z; c[3][3] += av.w * bv.w;
        }
        __syncthreads();
    }

    if (!ZHEAD) {
        #pragma unroll
        for (int i = 0; i < 4; ++i) {
            const int row = base + row4 + i;
            if (row < N_NODES) {
                float4 o;
                o.x = fmaxf(c[i][0], 0.f); o.y = fmaxf(c[i][1], 0.f);
                o.z = fmaxf(c[i][2], 0.f); o.w = fmaxf(c[i][3], 0.f);
                *(float4*)&out[(size_t)row * H + col4] = o;
            }
        }
    } else {
        float* Us = At;
        #pragma unroll
        for (int i = 0; i < 4; ++i)
            #pragma unroll
            for (int jj = 0; jj < 4; ++jj)
                Us[(row4 + i) * 65 + col4 + jj] = fmaxf(c[i][jj], 0.f);
        __syncthreads();
        if (tid < 128) {
            const int r = tid & 63, o = tid >> 6;
            const int row = base + r;
            if (row < N_NODES) {
                float v = 0.f;
                for (int k = 0; k < 64; ++k)
                    v += Us[r * 65 + k] * headW[o * 64 + k];
                z[(size_t)row * 2 + o] = v;
            }
        }
    }
}

// ---------- final: out[n] = mean_p(z) + a1[n] @ Wr'^T + b' ; wave per node ----------
__global__ __launch_bounds__(256) void final_head(
    const int* __restrict__ off, const int* __restrict__ csr,
    const float* __restrict__ z, const float* __restrict__ a1,
    const float* __restrict__ headW, float* __restrict__ out)
{
    const int node = (blockIdx.x * 256 + threadIdx.x) >> 6;
    const int lane = threadIdx.x & 63;
    const int beg = off[node], end = off[node + 1];
    float z0 = 0.f, z1 = 0.f;
    for (int e = beg + lane; e < end; e += 64) {
        int s = csr[e];
        const float2 zv = *(const float2*)&z[(size_t)s * 2];
        z0 += zv.x; z1 += zv.y;
    }
    const float av = a1[(size_t)node * H + lane];
    float p0 = av * headW[128 + lane];
    float p1 = av * headW[192 + lane];
    #pragma unroll
    for (int m = 1; m <= 32; m <<= 1) {
        z0 += __shfl_xor(z0, m, 64);
        z1 += __shfl_xor(z1, m, 64);
        p0 += __shfl_xor(p0, m, 64);
        p1 += __shfl_xor(p1, m, 64);
    }
    if (lane == 0) {
        const float inv = 1.0f / fmaxf((float)(end - beg), 1.0f);
        float2 o;
        o.x = z0 * inv + p0 + headW[256];
        o.y = z1 * inv + p1 + headW[257];
        *(float2*)&out[(size_t)node * 2] = o;
    }
}

extern "C" void kernel_launch(void* const* d_in, const int* in_sizes, int n_in,
                              void* d_out, int out_size, void* d_ws, size_t ws_size,
                              hipStream_t stream) {
    const float* x_a    = (const float*)d_in[0];
    const float* x_u    = (const float*)d_in[1];
    const int*   ei_p   = (const int*)d_in[2];
    const int*   ei_b   = (const int*)d_in[3];
    const float* w_in_a = (const float*)d_in[4];
    const float* b_in_a = (const float*)d_in[5];
    const float* w_in_u = (const float*)d_in[6];
    const float* b_in_u = (const float*)d_in[7];
    const float* c1p_wl = (const float*)d_in[8];
    const float* c1p_bl = (const float*)d_in[9];
    const float* c1p_wr = (const float*)d_in[10];
    const float* c1b_wl = (const float*)d_in[11];
    const float* c1b_bl = (const float*)d_in[12];
    const float* c1b_wr = (const float*)d_in[13];
    const float* c2p_wl = (const float*)d_in[14];
    const float* c2p_bl = (const float*)d_in[15];
    const float* c2p_wr = (const float*)d_in[16];
    const float* w_out  = (const float*)d_in[20];
    const float* b_out  = (const float*)d_in[21];

    const size_t NF = (size_t)N_NODES * H;
    float* bufA  = (float*)d_ws;
    float* bufU  = bufA + NF;
    float* agg   = bufU + NF;          // also aliases raw CSR scratch (pre-gather only)
    float* z     = agg + NF;
    float* headW = z + 2 * N_NODES;
    int* off_p  = (int*)(headW + 512);
    int* off_b  = off_p + OFFPAD;
    int* boff_p = off_b + OFFPAD;      // NBKT+1 (pad 2048)
    int* boff_b = boff_p + 2048;
    int* gcur_p = boff_b + 2048;
    int* gcur_b = gcur_p + 2048;
    int* hist_p = gcur_b + 2048;
    int* hist_b = hist_p + OFFPAD;
    int* bsum_p = hist_b + OFFPAD;
    int* bsum_b = bsum_p + 256;
    int* bpre_p = bsum_b + 256;
    int* bpre_b = bpre_p + 256;
    int* csr_p  = bpre_b + 256;
    int* csr_b  = csr_p + EDGES;
    int* raw_p  = (int*)agg;           // 2*EDGES ints fit in NF floats
    int* raw_b  = raw_p + EDGES;

    const dim3 blk(256);
    const int grid_edge = EDGES / 256;           // 6250
    const int grid_gemm = (N_NODES + 63) / 64;   // 1563
    const int grid_wave = N_NODES / 4;           // 25000

    // --- two-level counting sort: hist -> scan -> bucket fill -> per-node scatter ---
    hipMemsetAsync(hist_p, 0, 2 * OFFPAD * sizeof(int), stream);
    hist_dst<<<grid_edge, blk, 0, stream>>>(ei_p, hist_p);
    hist_dst<<<grid_edge, blk, 0, stream>>>(ei_b, hist_b);
    scan_partial<<<SCAN_BLKS, blk, 0, stream>>>(hist_p, bsum_p);
    scan_partial<<<SCAN_BLKS, blk, 0, stream>>>(hist_b, bsum_b);
    scan_tops<<<1, blk, 0, stream>>>(bsum_p, bpre_p);
    scan_tops<<<1, blk, 0, stream>>>(bsum_b, bpre_b);
    scan_apply<<<SCAN_BLKS, 512, 0, stream>>>(hist_p, bpre_p, off_p, boff_p, gcur_p);
    scan_apply<<<SCAN_BLKS, 512, 0, stream>>>(hist_b, bpre_b, off_b, boff_b, gcur_b);
    sort_fill<<<2 * FILL_BLKS, blk, 0, stream>>>(ei_p, ei_b, gcur_p, gcur_b, raw_p, raw_b);
    bucket_sort2<<<NBKT, blk, 0, stream>>>(raw_p, off_p, boff_p, csr_p);
    bucket_sort2<<<NBKT, blk, 0, stream>>>(raw_b, off_b, boff_b, csr_b);

    // --- input projections (MFMA, bf16-split) ---
    proj_mfma<300><<<grid_gemm, blk, 0, stream>>>(x_a, w_in_a, b_in_a, bufA);
    proj_mfma<64> <<<grid_gemm, blk, 0, stream>>>(x_u, w_in_u, b_in_u, bufU);

    fold_head<<<1, blk, 0, stream>>>(w_out, c2p_wl, c2p_wr, c2p_bl, b_out, headW);

    // user side: agg articles (ei_pb), z = relu(sage)@Wl'^T (u1 never stored)
    gather_mean<<<grid_wave, blk, 0, stream>>>(bufA, off_b, csr_b, agg);
    sage_node<true><<<grid_gemm, blk, 0, stream>>>(
        agg, bufU, c1b_wl, c1b_bl, c1b_wr, nullptr, headW, z);

    // article side: agg users (ei_posts), a1 in-place over bufA
    gather_mean<<<grid_wave, blk, 0, stream>>>(bufU, off_p, csr_p, agg);
    sage_node<false><<<grid_gemm, blk, 0, stream>>>(
        agg, bufA, c1p_wl, c1p_bl, c1p_wr, bufA, nullptr, nullptr);

    final_head<<<grid_wave, blk, 0, stream>>>(off_p, csr_p, z, bufA, headW, (float*)d_out);

    (void)in_sizes; (void)n_in; (void)out_size; (void)ws_size;
}